// Round 3
// baseline (595.846 us; speedup 1.0000x reference)
//
#include <hip/hip_runtime.h>
#include <math.h>

typedef __attribute__((ext_vector_type(8))) short bf16x8;
typedef __attribute__((ext_vector_type(4))) float f32x4;

__device__ inline unsigned short f2bf(float x){
  unsigned u = __builtin_bit_cast(unsigned, x);
  u = (u + 0x7FFFu + ((u >> 16) & 1u)) >> 16;
  return (unsigned short)u;
}

__device__ inline void gl16(const void* g, void* l){
  __builtin_amdgcn_global_load_lds(
      (const __attribute__((address_space(1))) unsigned int*)g,
      (__attribute__((address_space(3))) unsigned int*)l, 16, 0, 0);
}

#define KVLEN 4096
#define QLEN  128
#define NH    32
#define NKVH  8
#define HD    128
#define HIDD  4096
#define NSPLIT 4
#define KVCHUNK (KVLEN / NSPLIT)

// ---------------- prep: dtype detection + per-batch RoPE tables ----------------
__global__ void prep_kernel(const int* __restrict__ pos32,
                            const unsigned int* __restrict__ mask32,
                            float* __restrict__ costab,
                            float* __restrict__ sintab,
                            int* __restrict__ flags){
  int tid = threadIdx.x;
  if (tid < 64){
    // u8 bool mask has nonzero bytes at offsets %4 != 0; int32 0/1 never does
    unsigned long long bal = __ballot((mask32[tid] & 0xFFFFFF00u) != 0);
    if (tid == 0) flags[0] = (bal != 0) ? 1 : 0;
  }
  int b = tid >> 6, j = tid & 63;          // 4 batches x 64 freqs
  // position dtype: if int64 (LE), the high word of element 4095 is 0.
  bool pos64 = (pos32[2*4095 + 1] == 0);
  long long mpos;
  if (pos64) mpos = ((const long long*)pos32)[(size_t)b*KVLEN + KVLEN - 1];
  else       mpos = (long long)pos32[(size_t)b*KVLEN + KVLEN - 1];
  // rows are sorted ascending -> last element is the max (what argmax picks)
  double inv = pow(10000.0, -((double)j) / 64.0);
  double ang = (double)mpos * inv;
  costab[b*64 + j] = (float)cos(ang);
  sintab[b*64 + j] = (float)sin(ang);
}

// ---------------- mask pack: bool[B,1,QL,KVL] -> u64 bitmask ----------------
__global__ __launch_bounds__(256) void maskpack_kernel(const void* __restrict__ mask,
                                                       const int* __restrict__ flags,
                                                       unsigned long long* __restrict__ bits){
  int idx = blockIdx.x * 256 + threadIdx.x;     // 4*128*4096 threads, kv fastest
  bool m8 = (flags[0] != 0);
  bool v = m8 ? (((const unsigned char*)mask)[idx] != 0)
              : (((const int*)mask)[idx] != 0);
  unsigned long long bal = __ballot(v);
  if ((threadIdx.x & 63) == 0) bits[idx >> 6] = bal;
}

// ---------------- kvprep: fp32 K,V -> bf16 attn-ready tile images ----------------
// grid: 2048 blocks = b*512 + kvh*64 + t; each handles one 64-kv tile.
// K image: 16KB = exact swizzled LDS content: byte((r*256+d*2)^((r&7)<<4)) = K[r][d]
// V image: fragment-linear: chunk c = ((d>>4)*2 + kv2>>5)*4 + (kv2>>3)&3)*16 + (d&15),
//          elem e = kv2&7 -> V[kv2][d]; attn loads bf16x8 chunks directly to VGPR.
__global__ __launch_bounds__(256) void kvprep_kernel(const float* __restrict__ Kg,
                                                     const float* __restrict__ Vg,
                                                     unsigned short* __restrict__ Kswz,
                                                     unsigned short* __restrict__ V2){
  __shared__ alignas(16) unsigned short tmp[8192];
  int bid = blockIdx.x;
  int tid = threadIdx.x;
  const float* kin = Kg + (size_t)bid * 8192;
  const float* vin = Vg + (size_t)bid * 8192;
  unsigned short* kout = Kswz + (size_t)bid * 8192;
  unsigned short* vout = V2   + (size_t)bid * 8192;
  // K: direct swizzled image write
#pragma unroll
  for (int i = 0; i < 4; ++i){
    int c = tid + 256*i;
    int r = c >> 4, d0 = (c & 15) * 8;
    f32x4 x0 = *(const f32x4*)(kin + r*128 + d0);
    f32x4 x1 = *(const f32x4*)(kin + r*128 + d0 + 4);
    bf16x8 s;
#pragma unroll
    for (int t = 0; t < 4; ++t){ s[t] = (short)f2bf(x0[t]); s[t+4] = (short)f2bf(x1[t]); }
    unsigned o = ((unsigned)(r*256 + d0*2)) ^ (((unsigned)r & 7u) << 4);
    *(bf16x8*)((char*)kout + o) = s;
  }
  // V: coalesced row read -> LDS transpose into fragment-linear image -> dump
#pragma unroll
  for (int i = 0; i < 4; ++i){
    int c = tid + 256*i;
    int kv2 = c >> 4, d0 = (c & 15) * 8;
    f32x4 x0 = *(const f32x4*)(vin + kv2*128 + d0);
    f32x4 x1 = *(const f32x4*)(vin + kv2*128 + d0 + 4);
    int ks2 = kv2 >> 5, lk4 = (kv2 >> 3) & 3, e = kv2 & 7;
#pragma unroll
    for (int j = 0; j < 8; ++j){
      int d = d0 + j;
      int cc = (((d >> 4)*2 + ks2)*4 + lk4)*16 + (d & 15);
      float v = (j < 4) ? x0[j] : x1[j-4];
      tmp[cc*8 + e] = f2bf(v);
    }
  }
  __syncthreads();
#pragma unroll
  for (int i = 0; i < 4; ++i){
    int c = tid + 256*i;
    *(bf16x8*)(vout + c*8) = *(const bf16x8*)(&tmp[c*8]);
  }
}

// ---------------- GEMM: C[M,N] = A[M,K](f32) * B[K,N](f32), bf16 MFMA ----------------
__global__ __launch_bounds__(256) void gemm_kernel(const float* __restrict__ A,
                                                   const float* __restrict__ B,
                                                   float* __restrict__ C,
                                                   int N, int K){
  __shared__ alignas(16) unsigned short Alds[64][40];
  __shared__ alignas(16) unsigned short Blds[128][40];
  int tid = threadIdx.x;
  int lane = tid & 63;
  int w = tid >> 6, wm = w >> 1, wn = w & 1;
  int l16 = lane & 15, lk4 = lane >> 4;
  int bm = blockIdx.y, bn = blockIdx.x;

  f32x4 acc[2][4] = {};

  int ar = tid >> 2, ac8 = (tid & 3) * 8;
  const float* Ap = A + (size_t)(bm*64 + ar) * K + ac8;
  int bcol = tid & 127, bkh = (tid >> 7) * 16;
  const float* Bp = B + (size_t)bkh * N + (size_t)bn * 128 + bcol;

  for (int k0 = 0; k0 < K; k0 += 32){
    {
      f32x4 a0 = *(const f32x4*)(Ap + k0);
      f32x4 a1 = *(const f32x4*)(Ap + k0 + 4);
      bf16x8 av;
#pragma unroll
      for (int t = 0; t < 4; ++t){ av[t] = (short)f2bf(a0[t]); av[t+4] = (short)f2bf(a1[t]); }
      *(bf16x8*)&Alds[ar][ac8] = av;
    }
    {
      const float* bp = Bp + (size_t)k0 * N;
      bf16x8 bv0, bv1;
#pragma unroll
      for (int i = 0; i < 8; ++i) bv0[i] = (short)f2bf(bp[(size_t)i * N]);
#pragma unroll
      for (int i = 0; i < 8; ++i) bv1[i] = (short)f2bf(bp[(size_t)(i+8) * N]);
      *(bf16x8*)&Blds[bcol][bkh]     = bv0;
      *(bf16x8*)&Blds[bcol][bkh + 8] = bv1;
    }
    __syncthreads();
    bf16x8 af[2], bfr[4];
#pragma unroll
    for (int i = 0; i < 2; ++i) af[i]  = *(const bf16x8*)&Alds[wm*32 + i*16 + l16][lk4*8];
#pragma unroll
    for (int j = 0; j < 4; ++j) bfr[j] = *(const bf16x8*)&Blds[wn*64 + j*16 + l16][lk4*8];
#pragma unroll
    for (int i = 0; i < 2; ++i)
#pragma unroll
      for (int j = 0; j < 4; ++j)
        acc[i][j] = __builtin_amdgcn_mfma_f32_16x16x32_bf16(af[i], bfr[j], acc[i][j], 0, 0, 0);
    __syncthreads();
  }
#pragma unroll
  for (int i = 0; i < 2; ++i)
#pragma unroll
    for (int j = 0; j < 4; ++j)
#pragma unroll
      for (int r = 0; r < 4; ++r){
        int row = bm*64 + wm*32 + i*16 + lk4*4 + r;
        int col = bn*128 + wn*64 + j*16 + l16;
        C[(size_t)row * N + col] = acc[i][j][r];
      }
}

// ---------------- RoPE + scale + bf16 cast ----------------
__global__ __launch_bounds__(256) void rope_kernel(const float* __restrict__ qpre,
                                                   const float* __restrict__ costab,
                                                   const float* __restrict__ sintab,
                                                   unsigned short* __restrict__ qbf){
  int idx = blockIdx.x * 256 + threadIdx.x;
  int half = idx & 63;
  int h    = (idx >> 6) & 31;
  int row  = idx >> 11;
  int b  = row >> 7;
  int ql = row & 127;
  float c = costab[b*64 + half];
  float s = sintab[b*64 + half];
  size_t base = (size_t)row * HIDD + (size_t)h * HD;
  float x1 = qpre[base + half];
  float x2 = qpre[base + half + 64];
  const float scale = 0.08838834764831845f;
  float y1 = (x1 * c - x2 * s) * scale;
  float y2 = (x2 * c + x1 * s) * scale;
  size_t ob = ((size_t)(b*NH + h) * QLEN + ql) * HD;
  qbf[ob + half]      = f2bf(y1);
  qbf[ob + half + 64] = f2bf(y2);
}

// ---------------- flash attention, KV-split + pipelined bf16 staging ----------------
__global__ __launch_bounds__(256, 3) void attn_kernel(const unsigned short* __restrict__ Q,
                                                      const unsigned short* __restrict__ Kswz,
                                                      const unsigned short* __restrict__ V2,
                                                      const unsigned long long* __restrict__ bits,
                                                      float* __restrict__ Opart,
                                                      float* __restrict__ Mpart,
                                                      float* __restrict__ Lpart){
  __shared__ alignas(16) unsigned short Kbuf[2][8192];   // double-buffered K tile images
  __shared__ alignas(16) unsigned short Plds[4][1024];   // per-wave P, swizzled
  int bid = blockIdx.x;
  int j = (bid >> 3) & 7;
  int g = (bid & 7) | ((bid >> 6) << 3);        // group = (b,kvh,s): 8 sharers -> same XCD
  int s   = g & 3;
  int kvh = (g >> 2) & 7;
  int b   = g >> 5;
  int hg  = j >> 1, qb = j & 1;
  int h   = kvh * 4 + hg;

  int tid = threadIdx.x, lane = tid & 63, w = tid >> 6;
  int l16 = lane & 15, lk4 = lane >> 4;

  bf16x8 qf[4];
  {
    const unsigned short* qp = Q + (((size_t)(b*NH + h) * QLEN) + qb*64 + w*16 + l16) * HD;
#pragma unroll
    for (int ks = 0; ks < 4; ++ks)
      qf[ks] = *(const bf16x8*)(qp + ks*32 + lk4*8);
  }
  f32x4 acc_o[8] = {};
  float mrun[4], lrun[4];
#pragma unroll
  for (int r = 0; r < 4; ++r){ mrun[r] = -1e30f; lrun[r] = 0.f; }

  size_t kvhbase = (size_t)(b*NKVH + kvh) * (KVLEN/64);          // tile index base
  const unsigned short* Ktiles = Kswz + kvhbase * 8192;
  const unsigned short* Vtiles = V2   + kvhbase * 8192;
  size_t bbase = ((size_t)(b*QLEN + qb*64 + w*16 + lk4*4)) << 6; // *64 words/row

  const int t0 = s * (KVCHUNK/64), t1 = t0 + KVCHUNK/64;

  // prologue: stage tile t0 into buf 0
  {
    const char* gk = (const char*)(Ktiles + (size_t)t0*8192) + w*4096 + lane*16;
    char* lk = (char*)(&Kbuf[0][0]) + w*4096;
#pragma unroll
    for (int i = 0; i < 4; ++i) gl16(gk + i*1024, lk + i*1024);
  }
  asm volatile("s_waitcnt vmcnt(0)" ::: "memory");
  __syncthreads();

  int cur = 0;
  for (int t = t0; t < t1; ++t){
    // issue next-tile K stage (async, drains at end-of-tile vmcnt)
    if (t + 1 < t1){
      const char* gk = (const char*)(Ktiles + (size_t)(t+1)*8192) + w*4096 + lane*16;
      char* lk = (char*)(&Kbuf[cur ^ 1][0]) + w*4096;
#pragma unroll
      for (int i = 0; i < 4; ++i) gl16(gk + i*1024, lk + i*1024);
    }
    // mask words for this tile (issue early)
    unsigned long long wrd[4];
#pragma unroll
    for (int r = 0; r < 4; ++r)
      wrd[r] = bits[bbase + (size_t)r*64 + (size_t)t];

    // ---- S = Q K^T from Kbuf[cur] ----
    f32x4 sacc[4] = {};
#pragma unroll
    for (int nf = 0; nf < 4; ++nf){
      int krow = nf*16 + l16;
#pragma unroll
      for (int ks = 0; ks < 4; ++ks){
        unsigned byteoff = ((unsigned)krow*256u + (unsigned)(ks*32 + lk4*8)*2u) ^ (((unsigned)krow & 7u) << 4);
        bf16x8 kf = *(const bf16x8*)((const char*)&Kbuf[cur][0] + byteoff);
        sacc[nf] = __builtin_amdgcn_mfma_f32_16x16x32_bf16(qf[ks], kf, sacc[nf], 0, 0, 0);
      }
    }

    // ---- V fragments direct to VGPR (latency hides under softmax) ----
    bf16x8 vf[8][2];
    {
      const unsigned short* Vt = Vtiles + (size_t)t*8192;
#pragma unroll
      for (int nf8 = 0; nf8 < 8; ++nf8)
#pragma unroll
        for (int ks2 = 0; ks2 < 2; ++ks2){
          int c = ((nf8*2 + ks2)*4 + lk4)*16 + l16;
          vf[nf8][ks2] = *(const bf16x8*)(Vt + c*8);
        }
    }

    // ---- mask + online softmax ----
    float p[4][4];
    float pmax[4];
#pragma unroll
    for (int r = 0; r < 4; ++r) pmax[r] = -1e30f;
#pragma unroll
    for (int nf = 0; nf < 4; ++nf)
#pragma unroll
      for (int r = 0; r < 4; ++r){
        bool mk = (wrd[r] >> (nf*16 + l16)) & 1ull;
        float sv = mk ? -10000.f : sacc[nf][r];
        p[nf][r] = sv;
        pmax[r] = fmaxf(pmax[r], sv);
      }
#pragma unroll
    for (int r = 0; r < 4; ++r){
#pragma unroll
      for (int mb = 1; mb < 16; mb <<= 1)
        pmax[r] = fmaxf(pmax[r], __shfl_xor(pmax[r], mb, 64));
    }
    float psum[4];
#pragma unroll
    for (int r = 0; r < 4; ++r){
      float mnew = fmaxf(mrun[r], pmax[r]);
      float corr = __expf(mrun[r] - mnew);
      mrun[r] = mnew;
      lrun[r] *= corr;
#pragma unroll
      for (int nf8 = 0; nf8 < 8; ++nf8) acc_o[nf8][r] *= corr;
      float ps = 0.f;
#pragma unroll
      for (int nf = 0; nf < 4; ++nf){
        float e = __expf(p[nf][r] - mnew);
        p[nf][r] = e;
        ps += e;
      }
      psum[r] = ps;
    }
#pragma unroll
    for (int r = 0; r < 4; ++r){
#pragma unroll
      for (int mb = 1; mb < 16; mb <<= 1)
        psum[r] += __shfl_xor(psum[r], mb, 64);
      lrun[r] += psum[r];
    }

    // ---- P -> per-wave LDS (C-layout -> A-layout) ----
    unsigned short* pw = &Plds[w][0];
#pragma unroll
    for (int nf = 0; nf < 4; ++nf)
#pragma unroll
      for (int r = 0; r < 4; ++r){
        unsigned prow = (unsigned)(lk4*4 + r);
        unsigned pcol = (unsigned)(nf*16 + l16);
        unsigned byteoff = (prow*128u + pcol*2u) ^ ((prow & 7u) << 4);
        *(unsigned short*)((char*)pw + byteoff) = f2bf(p[nf][r]);
      }
    // per-wave LDS: in-order DS queue; fence compiler + drain lgkm (not vmcnt)
    __builtin_amdgcn_sched_barrier(0);
    asm volatile("s_waitcnt lgkmcnt(0)" ::: "memory");
    __builtin_amdgcn_sched_barrier(0);

    // ---- O += P V ----
    bf16x8 pf[2];
#pragma unroll
    for (int ks2 = 0; ks2 < 2; ++ks2){
      unsigned byteoff = ((unsigned)l16*128u + (unsigned)(ks2*32 + lk4*8)*2u) ^ (((unsigned)l16 & 7u) << 4);
      pf[ks2] = *(const bf16x8*)((const char*)pw + byteoff);
    }
#pragma unroll
    for (int nf8 = 0; nf8 < 8; ++nf8)
#pragma unroll
      for (int ks2 = 0; ks2 < 2; ++ks2)
        acc_o[nf8] = __builtin_amdgcn_mfma_f32_16x16x32_bf16(pf[ks2], vf[nf8][ks2], acc_o[nf8], 0, 0, 0);

    // end of tile: drain staged K(t+1), all waves done with Kbuf[cur]
    asm volatile("s_waitcnt vmcnt(0)" ::: "memory");
    __syncthreads();
    cur ^= 1;
  }

  // ---- epilogue: unnormalized partials + (m,l) ----
  size_t rowbase = ((size_t)(s*4 + b) * NH + h) * QLEN + qb*64 + w*16 + lk4*4;
#pragma unroll
  for (int nf8 = 0; nf8 < 8; ++nf8)
#pragma unroll
    for (int r = 0; r < 4; ++r){
      int col = nf8*16 + l16;
      Opart[(rowbase + r) * HD + col] = acc_o[nf8][r];
    }
  if (l16 == 0){
#pragma unroll
    for (int r = 0; r < 4; ++r){
      Mpart[rowbase + r] = mrun[r];
      Lpart[rowbase + r] = lrun[r];
    }
  }
}

// ---------------- combine: merge NSPLIT partials (f32x4 per thread) ----------------
__global__ __launch_bounds__(256) void combine_kernel(const float* __restrict__ Opart,
                                                      const float* __restrict__ Mpart,
                                                      const float* __restrict__ Lpart,
                                                      float* __restrict__ attno){
  int idx = blockIdx.x * 256 + threadIdx.x;     // B*H*QL*D/4 = 524288 threads
  int d4 = idx & 31;
  int row = idx >> 5;                           // (b*32+h)*128 + ql
  const int RS = 4 * NH * QLEN;
  float m[NSPLIT];
#pragma unroll
  for (int s = 0; s < NSPLIT; ++s) m[s] = Mpart[(size_t)s*RS + row];
  float M = fmaxf(fmaxf(m[0], m[1]), fmaxf(m[2], m[3]));
  float L = 0.f;
  f32x4 num = {};
#pragma unroll
  for (int s = 0; s < NSPLIT; ++s){
    float wsc = __expf(m[s] - M);
    L += wsc * Lpart[(size_t)s*RS + row];
    f32x4 o = *(const f32x4*)&Opart[((size_t)s*RS + row) * HD + d4*4];
#pragma unroll
    for (int t = 0; t < 4; ++t) num[t] += wsc * o[t];
  }
  int ql = row & 127, h = (row >> 7) & 31, b = row >> 12;
  f32x4 res;
#pragma unroll
  for (int t = 0; t < 4; ++t) res[t] = num[t] / L;
  *(f32x4*)&attno[((size_t)(b*QLEN + ql)) * HIDD + h*HD + d4*4] = res;
}

// ---------------- launch ----------------
extern "C" void kernel_launch(void* const* d_in, const int* in_sizes, int n_in,
                              void* d_out, int out_size, void* d_ws, size_t ws_size,
                              hipStream_t stream){
  (void)in_sizes; (void)n_in; (void)out_size; (void)ws_size;
  const float* hidden = (const float*)d_in[0];
  const float* kst    = (const float*)d_in[1];
  const float* vst    = (const float*)d_in[2];
  const float* wq     = (const float*)d_in[3];
  const float* wo     = (const float*)d_in[4];
  const void*  pos    = d_in[5];
  const void*  mask   = d_in[6];
  float* out = (float*)d_out;

  char* ws = (char*)d_ws;
  float* Opart = (float*)ws;                                    // 32 MiB
  float* qpre  = (float*)(ws + (32u << 20));                    // 8 MiB (reused as attno)
  unsigned short* qbf  = (unsigned short*)(ws + (40u << 20));   // 4 MiB
  unsigned short* Kswz = (unsigned short*)(ws + (44u << 20));   // 32 MiB
  unsigned short* V2   = (unsigned short*)(ws + (76u << 20));   // 32 MiB
  float* Mpart = (float*)(ws + (108u << 20));                   // 256 KiB
  float* Lpart = (float*)(ws + (108u << 20) + (256u << 10));    // 256 KiB
  unsigned long long* bits = (unsigned long long*)(ws + (108u << 20) + (512u << 10)); // 256 KiB
  float* costab = (float*)(ws + (109u << 20));
  float* sintab = costab + 256;
  int*   flags  = (int*)(sintab + 256);
  float* attno = qpre;

  prep_kernel<<<1, 256, 0, stream>>>((const int*)pos, (const unsigned int*)mask,
                                     costab, sintab, flags);
  maskpack_kernel<<<8192, 256, 0, stream>>>(mask, flags, bits);
  kvprep_kernel<<<2048, 256, 0, stream>>>(kst, vst, Kswz, V2);
  gemm_kernel<<<dim3(32, 8), 256, 0, stream>>>(hidden, wq, qpre, HIDD, HIDD);
  rope_kernel<<<4096, 256, 0, stream>>>(qpre, costab, sintab, qbf);
  attn_kernel<<<1024, 256, 0, stream>>>(qbf, Kswz, V2, bits, Opart, Mpart, Lpart);
  combine_kernel<<<2048, 256, 0, stream>>>(Opart, Mpart, Lpart, attno);
  gemm_kernel<<<dim3(32, 8), 256, 0, stream>>>(attno, wo, out, HIDD, HIDD);
}

// Round 4
// 388.512 us; speedup vs baseline: 1.5337x; 1.5337x over previous
//
#include <hip/hip_runtime.h>
#include <math.h>

typedef __attribute__((ext_vector_type(8))) short bf16x8;
typedef __attribute__((ext_vector_type(4))) float f32x4;

__device__ inline unsigned short f2bf(float x){
  unsigned u = __builtin_bit_cast(unsigned, x);
  u = (u + 0x7FFFu + ((u >> 16) & 1u)) >> 16;
  return (unsigned short)u;
}

__device__ inline void gl16(const void* g, void* l){
  __builtin_amdgcn_global_load_lds(
      (const __attribute__((address_space(1))) unsigned int*)g,
      (__attribute__((address_space(3))) unsigned int*)l, 16, 0, 0);
}

#define KVLEN 4096
#define QLEN  128
#define NH    32
#define NKVH  8
#define HD    128
#define HIDD  4096
#define NSPLIT 4
#define KVCHUNK (KVLEN / NSPLIT)

// ---------------- prep: dtype detection + per-batch RoPE tables ----------------
__global__ void prep_kernel(const int* __restrict__ pos32,
                            const unsigned int* __restrict__ mask32,
                            float* __restrict__ costab,
                            float* __restrict__ sintab,
                            int* __restrict__ flags){
  int tid = threadIdx.x;
  if (tid < 64){
    unsigned long long bal = __ballot((mask32[tid] & 0xFFFFFF00u) != 0);
    if (tid == 0) flags[0] = (bal != 0) ? 1 : 0;
  }
  int b = tid >> 6, j = tid & 63;          // 4 batches x 64 freqs
  bool pos64 = (pos32[2*4095 + 1] == 0);
  long long mpos;
  if (pos64) mpos = ((const long long*)pos32)[(size_t)b*KVLEN + KVLEN - 1];
  else       mpos = (long long)pos32[(size_t)b*KVLEN + KVLEN - 1];
  double inv = pow(10000.0, -((double)j) / 64.0);
  double ang = (double)mpos * inv;
  costab[b*64 + j] = (float)cos(ang);
  sintab[b*64 + j] = (float)sin(ang);
}

// ---------------- mask pack: bool[B,1,QL,KVL] -> u64 bitmask ----------------
__global__ __launch_bounds__(256) void maskpack_kernel(const void* __restrict__ mask,
                                                       const int* __restrict__ flags,
                                                       unsigned long long* __restrict__ bits){
  int idx = blockIdx.x * 256 + threadIdx.x;
  bool m8 = (flags[0] != 0);
  bool v = m8 ? (((const unsigned char*)mask)[idx] != 0)
              : (((const int*)mask)[idx] != 0);
  unsigned long long bal = __ballot(v);
  if ((threadIdx.x & 63) == 0) bits[idx >> 6] = bal;
}

// ---------------- kvprep: fp32 K,V -> bf16 attn-ready tile images ----------------
// K image: exact swizzled LDS bytes: byte((r*256+d*2)^((r&7)<<4)) = K[r][d]
// V image: fragment-linear: u16 index c*8+e, c=((nf8*2+ks2)*4+lk4)*16+l16,
//          holds V[ks2*32+lk4*8+e][nf8*16+l16].
__global__ __launch_bounds__(256) void kvprep_kernel(const float* __restrict__ Kg,
                                                     const float* __restrict__ Vg,
                                                     unsigned short* __restrict__ Kswz,
                                                     unsigned short* __restrict__ V2){
  int bid = blockIdx.x;
  int tid = threadIdx.x;
  const float* kin = Kg + (size_t)bid * 8192;
  const float* vin = Vg + (size_t)bid * 8192;
  unsigned short* kout = Kswz + (size_t)bid * 8192;
  unsigned short* vout = V2   + (size_t)bid * 8192;
  // K: vectorized row reads -> swizzled image
#pragma unroll
  for (int i = 0; i < 4; ++i){
    int c = tid + 256*i;
    int r = c >> 4, d0 = (c & 15) * 8;
    f32x4 x0 = *(const f32x4*)(kin + r*128 + d0);
    f32x4 x1 = *(const f32x4*)(kin + r*128 + d0 + 4);
    bf16x8 s;
#pragma unroll
    for (int t = 0; t < 4; ++t){ s[t] = (short)f2bf(x0[t]); s[t+4] = (short)f2bf(x1[t]); }
    unsigned o = ((unsigned)(r*256 + d0*2)) ^ (((unsigned)r & 7u) << 4);
    *(bf16x8*)((char*)kout + o) = s;
  }
  // V: gather transpose (no LDS); each thread owns one 16B output chunk
#pragma unroll
  for (int i = 0; i < 4; ++i){
    int c = tid + 256*i;
    int l16 = c & 15, lk4 = (c >> 4) & 3, ks2 = (c >> 6) & 1, nf8 = c >> 7;
    int d = nf8*16 + l16;
    int kvb = ks2*32 + lk4*8;
    bf16x8 s;
#pragma unroll
    for (int e = 0; e < 8; ++e) s[e] = (short)f2bf(vin[(size_t)(kvb + e)*128 + d]);
    *(bf16x8*)(vout + (size_t)c*8) = s;
  }
}

// ---------------- GEMM: C[M,N] = A[M,K] * B[K,N](f32), bf16 MFMA ----------------
// BM=64 BN=128 BK=32, 4 waves, each wave: 16 rows x 128 cols (4x1 tiling)
// ABF16: A is bf16 (no convert). EPI=1: RoPE+scale epilogue -> bf16 qbf out.
template<bool ABF16, int EPI>
__global__ __launch_bounds__(256) void gemm_kernel(const void* __restrict__ A_,
                                                   const float* __restrict__ B,
                                                   void* __restrict__ C_,
                                                   const float* __restrict__ costab,
                                                   const float* __restrict__ sintab,
                                                   int N, int K){
  __shared__ alignas(16) unsigned short Alds[64][40];
  __shared__ alignas(16) unsigned short Blds[128][40];
  int tid = threadIdx.x;
  int lane = tid & 63;
  int w = tid >> 6;
  int l16 = lane & 15, lk4 = lane >> 4;
  int bm = blockIdx.y, bn = blockIdx.x;

  f32x4 acc[8] = {};

  int ar = tid >> 2, ac8 = (tid & 3) * 8;
  int bcol = tid & 127, bkh = (tid >> 7) * 16;
  const float* Bp = B + (size_t)bkh * N + (size_t)bn * 128 + bcol;

  for (int k0 = 0; k0 < K; k0 += 32){
    // stage A
    if (ABF16){
      const unsigned short* Ap = (const unsigned short*)A_ + (size_t)(bm*64 + ar) * K + ac8 + k0;
      *(bf16x8*)&Alds[ar][ac8] = *(const bf16x8*)Ap;
    } else {
      const float* Ap = (const float*)A_ + (size_t)(bm*64 + ar) * K + ac8 + k0;
      f32x4 a0 = *(const f32x4*)(Ap);
      f32x4 a1 = *(const f32x4*)(Ap + 4);
      bf16x8 av;
#pragma unroll
      for (int t = 0; t < 4; ++t){ av[t] = (short)f2bf(a0[t]); av[t+4] = (short)f2bf(a1[t]); }
      *(bf16x8*)&Alds[ar][ac8] = av;
    }
    // stage B (transposed [n][k])
    {
      const float* bp = Bp + (size_t)k0 * N;
      bf16x8 bv0, bv1;
#pragma unroll
      for (int i = 0; i < 8; ++i) bv0[i] = (short)f2bf(bp[(size_t)i * N]);
#pragma unroll
      for (int i = 0; i < 8; ++i) bv1[i] = (short)f2bf(bp[(size_t)(i+8) * N]);
      *(bf16x8*)&Blds[bcol][bkh]     = bv0;
      *(bf16x8*)&Blds[bcol][bkh + 8] = bv1;
    }
    __syncthreads();
    bf16x8 af = *(const bf16x8*)&Alds[w*16 + l16][lk4*8];
#pragma unroll
    for (int j = 0; j < 8; ++j){
      bf16x8 bf = *(const bf16x8*)&Blds[j*16 + l16][lk4*8];
      acc[j] = __builtin_amdgcn_mfma_f32_16x16x32_bf16(af, bf, acc[j], 0, 0, 0);
    }
    __syncthreads();
  }

  if (EPI == 0){
    float* C = (float*)C_;
#pragma unroll
    for (int j = 0; j < 8; ++j)
#pragma unroll
      for (int r = 0; r < 4; ++r){
        int row = bm*64 + w*16 + lk4*4 + r;
        int col = bn*128 + j*16 + l16;
        C[(size_t)row * N + col] = acc[j][r];
      }
  } else {
    // RoPE + 1/sqrt(D) + bf16; out layout [b][h][ql][d]
    unsigned short* Q = (unsigned short*)C_;
    int b = bm >> 1, h = bn;
    const float scale = 0.08838834764831845f;
    float cs[4], sn[4];
#pragma unroll
    for (int j = 0; j < 4; ++j){
      int half = j*16 + l16;
      cs[j] = costab[b*64 + half];
      sn[j] = sintab[b*64 + half];
    }
#pragma unroll
    for (int r = 0; r < 4; ++r){
      int ql = (bm & 1)*64 + w*16 + lk4*4 + r;
      size_t ob = ((size_t)(b*NH + h) * QLEN + ql) * HD;
#pragma unroll
      for (int j = 0; j < 4; ++j){
        float y1 = (acc[j][r]   * cs[j] - acc[j+4][r] * sn[j]) * scale;
        float y2 = (acc[j+4][r] * cs[j] + acc[j][r]   * sn[j]) * scale;
        Q[ob + j*16 + l16]      = f2bf(y1);
        Q[ob + 64 + j*16 + l16] = f2bf(y2);
      }
    }
  }
}

// ---------------- flash attention: KV-split, K+V double-buffered via global_load_lds ----------------
__global__ __launch_bounds__(256, 2) void attn_kernel(const unsigned short* __restrict__ Q,
                                                      const unsigned short* __restrict__ Kswz,
                                                      const unsigned short* __restrict__ V2,
                                                      const unsigned long long* __restrict__ bits,
                                                      float* __restrict__ Opart,
                                                      float* __restrict__ Mpart,
                                                      float* __restrict__ Lpart){
  __shared__ alignas(16) unsigned short Kbuf[2][8192];
  __shared__ alignas(16) unsigned short Vbuf[2][8192];
  __shared__ alignas(16) unsigned short Plds[4][1024];
  int bid = blockIdx.x;
  int j = (bid >> 3) & 7;
  int g = (bid & 7) | ((bid >> 6) << 3);        // 8 sharers of (b,kvh,s) -> same XCD
  int s   = g & 3;
  int kvh = (g >> 2) & 7;
  int b   = g >> 5;
  int hg  = j >> 1, qb = j & 1;
  int h   = kvh * 4 + hg;

  int tid = threadIdx.x, lane = tid & 63, w = tid >> 6;
  int l16 = lane & 15, lk4 = lane >> 4;

  bf16x8 qf[4];
  {
    const unsigned short* qp = Q + (((size_t)(b*NH + h) * QLEN) + qb*64 + w*16 + l16) * HD;
#pragma unroll
    for (int ks = 0; ks < 4; ++ks)
      qf[ks] = *(const bf16x8*)(qp + ks*32 + lk4*8);
  }
  f32x4 acc_o[8] = {};
  float mrun[4], lrun[4];
#pragma unroll
  for (int r = 0; r < 4; ++r){ mrun[r] = -1e30f; lrun[r] = 0.f; }

  size_t kvhbase = (size_t)(b*NKVH + kvh) * (KVLEN/64);
  const unsigned short* Ktiles = Kswz + kvhbase * 8192;
  const unsigned short* Vtiles = V2   + kvhbase * 8192;
  size_t bbase = ((size_t)(b*QLEN + qb*64 + w*16 + lk4*4)) << 6;

  const int t0 = s * (KVCHUNK/64), t1 = t0 + KVCHUNK/64;

  // stage tile -> buffers (per-wave 4KB quarters; LDS dest identity-mapped)
#define STAGE(T, BUF) do { \
    const char* gk_ = (const char*)(Ktiles + (size_t)(T)*8192) + w*4096 + lane*16; \
    const char* gv_ = (const char*)(Vtiles + (size_t)(T)*8192) + w*4096 + lane*16; \
    char* lk_ = (char*)(&Kbuf[BUF][0]) + w*4096; \
    char* lv_ = (char*)(&Vbuf[BUF][0]) + w*4096; \
    _Pragma("unroll") for (int i_ = 0; i_ < 4; ++i_) gl16(gk_ + i_*1024, lk_ + i_*1024); \
    _Pragma("unroll") for (int i_ = 0; i_ < 4; ++i_) gl16(gv_ + i_*1024, lv_ + i_*1024); \
  } while(0)

  STAGE(t0, 0);
  asm volatile("s_waitcnt vmcnt(0)" ::: "memory");
  __syncthreads();

  int cur = 0;
  for (int t = t0; t < t1; ++t){
    if (t + 1 < t1) STAGE(t + 1, cur ^ 1);
    unsigned long long wrd[4];
#pragma unroll
    for (int r = 0; r < 4; ++r)
      wrd[r] = bits[bbase + (size_t)r*64 + (size_t)t];
    __builtin_amdgcn_sched_barrier(0);   // pin stage + mask issue before compute

    // ---- S = Q K^T from Kbuf[cur] ----
    f32x4 sacc[4] = {};
#pragma unroll
    for (int nf = 0; nf < 4; ++nf){
      int krow = nf*16 + l16;
#pragma unroll
      for (int ks = 0; ks < 4; ++ks){
        unsigned byteoff = ((unsigned)krow*256u + (unsigned)(ks*32 + lk4*8)*2u) ^ (((unsigned)krow & 7u) << 4);
        bf16x8 kf = *(const bf16x8*)((const char*)&Kbuf[cur][0] + byteoff);
        sacc[nf] = __builtin_amdgcn_mfma_f32_16x16x32_bf16(qf[ks], kf, sacc[nf], 0, 0, 0);
      }
    }

    // ---- mask + online softmax ----
    float p[4][4];
    float pmax[4];
#pragma unroll
    for (int r = 0; r < 4; ++r) pmax[r] = -1e30f;
#pragma unroll
    for (int nf = 0; nf < 4; ++nf)
#pragma unroll
      for (int r = 0; r < 4; ++r){
        bool mk = (wrd[r] >> (nf*16 + l16)) & 1ull;
        float sv = mk ? -10000.f : sacc[nf][r];
        p[nf][r] = sv;
        pmax[r] = fmaxf(pmax[r], sv);
      }
#pragma unroll
    for (int r = 0; r < 4; ++r){
#pragma unroll
      for (int mb = 1; mb < 16; mb <<= 1)
        pmax[r] = fmaxf(pmax[r], __shfl_xor(pmax[r], mb, 64));
    }
    float psum[4];
#pragma unroll
    for (int r = 0; r < 4; ++r){
      float mnew = fmaxf(mrun[r], pmax[r]);
      float corr = __expf(mrun[r] - mnew);
      mrun[r] = mnew;
      lrun[r] *= corr;
#pragma unroll
      for (int nf8 = 0; nf8 < 8; ++nf8) acc_o[nf8][r] *= corr;
      float ps = 0.f;
#pragma unroll
      for (int nf = 0; nf < 4; ++nf){
        float e = __expf(p[nf][r] - mnew);
        p[nf][r] = e;
        ps += e;
      }
      psum[r] = ps;
    }
#pragma unroll
    for (int r = 0; r < 4; ++r){
#pragma unroll
      for (int mb = 1; mb < 16; mb <<= 1)
        psum[r] += __shfl_xor(psum[r], mb, 64);
      lrun[r] += psum[r];
    }

    // ---- P -> per-wave LDS (C-layout -> A-layout) ----
    unsigned short* pw = &Plds[w][0];
#pragma unroll
    for (int nf = 0; nf < 4; ++nf)
#pragma unroll
      for (int r = 0; r < 4; ++r){
        unsigned prow = (unsigned)(lk4*4 + r);
        unsigned pcol = (unsigned)(nf*16 + l16);
        unsigned byteoff = (prow*128u + pcol*2u) ^ ((prow & 7u) << 4);
        *(unsigned short*)((char*)pw + byteoff) = f2bf(p[nf][r]);
      }
    __builtin_amdgcn_sched_barrier(0);
    asm volatile("s_waitcnt lgkmcnt(0)" ::: "memory");
    __builtin_amdgcn_sched_barrier(0);

    // ---- O += P V from Vbuf[cur] ----
    bf16x8 pf[2];
#pragma unroll
    for (int ks2 = 0; ks2 < 2; ++ks2){
      unsigned byteoff = ((unsigned)l16*128u + (unsigned)(ks2*32 + lk4*8)*2u) ^ (((unsigned)l16 & 7u) << 4);
      pf[ks2] = *(const bf16x8*)((const char*)pw + byteoff);
    }
#pragma unroll
    for (int nf8 = 0; nf8 < 8; ++nf8)
#pragma unroll
      for (int ks2 = 0; ks2 < 2; ++ks2){
        unsigned byteoff = (unsigned)(nf8*2 + ks2)*1024u + (unsigned)lane*16u;
        bf16x8 vf = *(const bf16x8*)((const char*)&Vbuf[cur][0] + byteoff);
        acc_o[nf8] = __builtin_amdgcn_mfma_f32_16x16x32_bf16(pf[ks2], vf, acc_o[nf8], 0, 0, 0);
      }

    asm volatile("s_waitcnt vmcnt(0)" ::: "memory");   // next-tile stages complete
    __syncthreads();
    cur ^= 1;
  }
#undef STAGE

  // ---- epilogue: unnormalized partials + (m,l) ----
  size_t rowbase = ((size_t)(s*4 + b) * NH + h) * QLEN + qb*64 + w*16 + lk4*4;
#pragma unroll
  for (int nf8 = 0; nf8 < 8; ++nf8)
#pragma unroll
    for (int r = 0; r < 4; ++r){
      int col = nf8*16 + l16;
      Opart[(rowbase + r) * HD + col] = acc_o[nf8][r];
    }
  if (l16 == 0){
#pragma unroll
    for (int r = 0; r < 4; ++r){
      Mpart[rowbase + r] = mrun[r];
      Lpart[rowbase + r] = lrun[r];
    }
  }
}

// ---------------- combine: merge NSPLIT partials -> bf16 attno ----------------
typedef __attribute__((ext_vector_type(4))) short s16x4;
__global__ __launch_bounds__(256) void combine_kernel(const float* __restrict__ Opart,
                                                      const float* __restrict__ Mpart,
                                                      const float* __restrict__ Lpart,
                                                      unsigned short* __restrict__ attno){
  int idx = blockIdx.x * 256 + threadIdx.x;
  int d4 = idx & 31;
  int row = idx >> 5;
  const int RS = 4 * NH * QLEN;
  float m[NSPLIT];
#pragma unroll
  for (int s = 0; s < NSPLIT; ++s) m[s] = Mpart[(size_t)s*RS + row];
  float M = fmaxf(fmaxf(m[0], m[1]), fmaxf(m[2], m[3]));
  float L = 0.f;
  f32x4 num = {};
#pragma unroll
  for (int s = 0; s < NSPLIT; ++s){
    float wsc = __expf(m[s] - M);
    L += wsc * Lpart[(size_t)s*RS + row];
    f32x4 o = *(const f32x4*)&Opart[((size_t)s*RS + row) * HD + d4*4];
#pragma unroll
    for (int t = 0; t < 4; ++t) num[t] += wsc * o[t];
  }
  int ql = row & 127, h = (row >> 7) & 31, b = row >> 12;
  s16x4 res;
#pragma unroll
  for (int t = 0; t < 4; ++t) res[t] = (short)f2bf(num[t] / L);
  *(s16x4*)&attno[((size_t)(b*QLEN + ql)) * HIDD + h*HD + d4*4] = res;
}

// ---------------- launch ----------------
extern "C" void kernel_launch(void* const* d_in, const int* in_sizes, int n_in,
                              void* d_out, int out_size, void* d_ws, size_t ws_size,
                              hipStream_t stream){
  (void)in_sizes; (void)n_in; (void)out_size; (void)ws_size;
  const float* hidden = (const float*)d_in[0];
  const float* kst    = (const float*)d_in[1];
  const float* vst    = (const float*)d_in[2];
  const float* wq     = (const float*)d_in[3];
  const float* wo     = (const float*)d_in[4];
  const void*  pos    = d_in[5];
  const void*  mask   = d_in[6];
  float* out = (float*)d_out;

  char* ws = (char*)d_ws;
  float* Opart = (float*)ws;                                    // 32 MiB
  unsigned short* attno = (unsigned short*)(ws + (32u << 20));  // 4 MiB bf16
  unsigned short* qbf  = (unsigned short*)(ws + (36u << 20));   // 4 MiB
  unsigned short* Kswz = (unsigned short*)(ws + (40u << 20));   // 32 MiB
  unsigned short* V2   = (unsigned short*)(ws + (72u << 20));   // 32 MiB
  float* Mpart = (float*)(ws + (104u << 20));                   // 256 KiB
  float* Lpart = (float*)(ws + (104u << 20) + (256u << 10));    // 256 KiB
  unsigned long long* bits = (unsigned long long*)(ws + (104u << 20) + (512u << 10)); // 2 MiB
  float* costab = (float*)(ws + (107u << 20));
  float* sintab = costab + 256;
  int*   flags  = (int*)(sintab + 256);

  prep_kernel<<<1, 256, 0, stream>>>((const int*)pos, (const unsigned int*)mask,
                                     costab, sintab, flags);
  maskpack_kernel<<<8192, 256, 0, stream>>>(mask, flags, bits);
  kvprep_kernel<<<2048, 256, 0, stream>>>(kst, vst, Kswz, V2);
  gemm_kernel<false,1><<<dim3(32, 8), 256, 0, stream>>>(hidden, wq, qbf, costab, sintab, HIDD, HIDD);
  attn_kernel<<<1024, 256, 0, stream>>>(qbf, Kswz, V2, bits, Opart, Mpart, Lpart);
  combine_kernel<<<2048, 256, 0, stream>>>(Opart, Mpart, Lpart, attno);
  gemm_kernel<true,0><<<dim3(32, 8), 256, 0, stream>>>(attno, wo, out, nullptr, nullptr, HIDD, HIDD);
}

// Round 5
// 267.543 us; speedup vs baseline: 2.2271x; 1.4521x over previous
//
#include <hip/hip_runtime.h>
#include <math.h>

typedef __attribute__((ext_vector_type(8))) short bf16x8;
typedef __attribute__((ext_vector_type(4))) float f32x4;
typedef __attribute__((ext_vector_type(4))) short s16x4;

__device__ inline unsigned short f2bf(float x){
  unsigned u = __builtin_bit_cast(unsigned, x);
  u = (u + 0x7FFFu + ((u >> 16) & 1u)) >> 16;
  return (unsigned short)u;
}

__device__ inline void gl16(const void* g, void* l){
  __builtin_amdgcn_global_load_lds(
      (const __attribute__((address_space(1))) unsigned int*)g,
      (__attribute__((address_space(3))) unsigned int*)l, 16, 0, 0);
}

#define KVLEN 4096
#define QLEN  128
#define NH    32
#define NKVH  8
#define HD    128
#define HIDD  4096
#define NSPLIT 4
#define KVCHUNK (KVLEN / NSPLIT)

// ---------------- prep: dtype detection + per-batch RoPE tables ----------------
__global__ void prep_kernel(const int* __restrict__ pos32,
                            const unsigned int* __restrict__ mask32,
                            float* __restrict__ costab,
                            float* __restrict__ sintab,
                            int* __restrict__ flags){
  int tid = threadIdx.x;
  if (tid < 64){
    unsigned long long bal = __ballot((mask32[tid] & 0xFFFFFF00u) != 0);
    if (tid == 0) flags[0] = (bal != 0) ? 1 : 0;
  }
  int b = tid >> 6, j = tid & 63;
  bool pos64 = (pos32[2*4095 + 1] == 0);
  long long mpos;
  if (pos64) mpos = ((const long long*)pos32)[(size_t)b*KVLEN + KVLEN - 1];
  else       mpos = (long long)pos32[(size_t)b*KVLEN + KVLEN - 1];
  double inv = pow(10000.0, -((double)j) / 64.0);
  double ang = (double)mpos * inv;
  costab[b*64 + j] = (float)cos(ang);
  sintab[b*64 + j] = (float)sin(ang);
}

// ---------------- mask pack: bool[B,1,QL,KVL] -> u64 bitmask ----------------
__global__ __launch_bounds__(256) void maskpack_kernel(const void* __restrict__ mask,
                                                       const int* __restrict__ flags,
                                                       unsigned long long* __restrict__ bits){
  int idx = blockIdx.x * 256 + threadIdx.x;
  bool m8 = (flags[0] != 0);
  bool v = m8 ? (((const unsigned char*)mask)[idx] != 0)
              : (((const int*)mask)[idx] != 0);
  unsigned long long bal = __ballot(v);
  if ((threadIdx.x & 63) == 0) bits[idx >> 6] = bal;
}

// ---------------- kvprep: fp32 K,V -> bf16 attn-ready tile images ----------------
// K image: swizzled LDS bytes: byte((r*256+d*2)^((r&7)<<4)) = K[r][d]  (via LDS, linear dump)
// V image: fragment-linear: u16 c*8+e, c=((nf8*2+ks2)*4+lk4)*16+l16 -> V[ks2*32+lk4*8+e][nf8*16+l16]
__global__ __launch_bounds__(256) void kvprep_kernel(const float* __restrict__ Kg,
                                                     const float* __restrict__ Vg,
                                                     unsigned short* __restrict__ Kswz,
                                                     unsigned short* __restrict__ V2){
  __shared__ alignas(16) char tl[16384];
  int bid = blockIdx.x;
  int tid = threadIdx.x;
  const float* kin = Kg + (size_t)bid * 8192;
  const float* vin = Vg + (size_t)bid * 8192;
  unsigned short* kout = Kswz + (size_t)bid * 8192;
  unsigned short* vout = V2   + (size_t)bid * 8192;
  // K: coalesced row reads -> swizzled LDS -> linear dump
#pragma unroll
  for (int i = 0; i < 4; ++i){
    int c = tid + 256*i;
    int r = c >> 4, d0 = (c & 15) * 8;
    f32x4 x0 = *(const f32x4*)(kin + r*128 + d0);
    f32x4 x1 = *(const f32x4*)(kin + r*128 + d0 + 4);
    bf16x8 s;
#pragma unroll
    for (int t = 0; t < 4; ++t){ s[t] = (short)f2bf(x0[t]); s[t+4] = (short)f2bf(x1[t]); }
    unsigned o = ((unsigned)(r*256 + d0*2)) ^ (((unsigned)r & 7u) << 4);
    *(bf16x8*)(tl + o) = s;
  }
  __syncthreads();
#pragma unroll
  for (int i = 0; i < 4; ++i)
    *(bf16x8*)((char*)kout + tid*16 + i*4096) = *(const bf16x8*)(tl + tid*16 + i*4096);
  // V: gather transpose, linear write
#pragma unroll
  for (int i = 0; i < 4; ++i){
    int c = tid + 256*i;
    int l16 = c & 15, lk4 = (c >> 4) & 3, ks2 = (c >> 6) & 1, nf8 = c >> 7;
    int d = nf8*16 + l16;
    int kvb = ks2*32 + lk4*8;
    bf16x8 s;
#pragma unroll
    for (int e = 0; e < 8; ++e) s[e] = (short)f2bf(vin[(size_t)(kvb + e)*128 + d]);
    *(bf16x8*)(vout + (size_t)c*8) = s;
  }
}

// ---------------- wprep: weights/hidden fp32 -> bf16 swizzled tile images ----------------
// B image (weights, B[k][n]): tiles (bn in [0,32), kt in [0,64)), 16KB:
//   byte((n*128 + k*2) ^ ((n&7)<<4)) = B[kt*64+k][bn*128+n]
// A image (hidden [512][4096]): tiles (bm in [0,8), kt in [0,64)), 8KB:
//   byte((m*128 + k*2) ^ ((m&7)<<4)) = A[bm*64+m][kt*64+k]
__global__ __launch_bounds__(256) void wprep_kernel(const float* __restrict__ Wq,
                                                    const float* __restrict__ Wo,
                                                    const float* __restrict__ hidden,
                                                    unsigned short* __restrict__ WqImg,
                                                    unsigned short* __restrict__ WoImg,
                                                    unsigned short* __restrict__ A1img){
  __shared__ alignas(16) char tl[16384];
  int bid = blockIdx.x, tid = threadIdx.x;
  if (bid < 4096){
    const float* W = (bid < 2048) ? Wq : Wo;
    unsigned short* img = (bid < 2048) ? WqImg : WoImg;
    int t = bid & 2047;
    int bn = t >> 6, kt = t & 63;
    char* outB = (char*)img + (size_t)t * 16384;
#pragma unroll
    for (int i = 0; i < 4; ++i){
      int c = tid + 256*i;
      int n = c & 127, kc = c >> 7;
      const float* src = W + (size_t)(kt*64 + kc*8) * HIDD + bn*128 + n;
      bf16x8 s;
#pragma unroll
      for (int e = 0; e < 8; ++e) s[e] = (short)f2bf(src[(size_t)e * HIDD]);
      unsigned off = ((unsigned)(n*128 + kc*16)) ^ (((unsigned)n & 7u) << 4);
      *(bf16x8*)(tl + off) = s;
    }
    __syncthreads();
#pragma unroll
    for (int i = 0; i < 4; ++i)
      *(bf16x8*)(outB + tid*16 + i*4096) = *(const bf16x8*)(tl + tid*16 + i*4096);
  } else {
    int t = bid - 4096;                 // [0,512)
    int bm = t >> 6, kt = t & 63;
    char* outA = (char*)A1img + (size_t)t * 8192;
#pragma unroll
    for (int i = 0; i < 2; ++i){
      int c = tid + 256*i;
      int m = c >> 3, kc = c & 7;
      const float* src = hidden + (size_t)(bm*64 + m) * HIDD + kt*64 + kc*8;
      f32x4 x0 = *(const f32x4*)src;
      f32x4 x1 = *(const f32x4*)(src + 4);
      bf16x8 s;
#pragma unroll
      for (int e = 0; e < 4; ++e){ s[e] = (short)f2bf(x0[e]); s[e+4] = (short)f2bf(x1[e]); }
      unsigned off = ((unsigned)(m*128 + kc*16)) ^ (((unsigned)m & 7u) << 4);
      *(bf16x8*)(tl + off) = s;
    }
    __syncthreads();
#pragma unroll
    for (int i = 0; i < 2; ++i)
      *(bf16x8*)(outA + tid*16 + i*4096) = *(const bf16x8*)(tl + tid*16 + i*4096);
  }
}

// ---------------- GEMM: 512x4096x4096, bf16 images, gl_lds double-buffered ----------------
// BM=64 BN=128 BK=64, 4 waves 2x2. EPI=0: fp32 C. EPI=1: RoPE via LDS roundtrip -> qbf.
template<int EPI>
__global__ __launch_bounds__(256) void gemm_kernel(const unsigned short* __restrict__ Aimg,
                                                   const unsigned short* __restrict__ Bimg,
                                                   void* __restrict__ C_,
                                                   const float* __restrict__ costab,
                                                   const float* __restrict__ sintab){
  __shared__ alignas(16) char smem[49152];
  auto Abuf = (unsigned short(*)[4096])smem;            // 2 x 8KB
  auto Bbuf = (unsigned short(*)[8192])(smem + 16384);  // 2 x 16KB
  int bid = blockIdx.x;
  int bn = (bid & 7) | ((bid >> 6) << 3);   // same bn -> same bid%8 -> same XCD (B-panel share)
  int bm = (bid >> 3) & 7;
  int tid = threadIdx.x, lane = tid & 63, w = tid >> 6;
  int wm = w >> 1, wn = w & 1;
  int l16 = lane & 15, lk4 = lane >> 4;
  const char* At = (const char*)Aimg + (size_t)bm * 64 * 8192;
  const char* Bt = (const char*)Bimg + (size_t)bn * 64 * 16384;
  f32x4 acc[2][4] = {};

#define GSTAGE(KT, BUF) do { \
    const char* ga_ = At + (size_t)(KT)*8192  + w*2048 + lane*16; \
    const char* gb_ = Bt + (size_t)(KT)*16384 + w*4096 + lane*16; \
    char* la_ = (char*)&Abuf[BUF][0] + w*2048; \
    char* lb_ = (char*)&Bbuf[BUF][0] + w*4096; \
    gl16(ga_, la_); gl16(ga_ + 1024, la_ + 1024); \
    _Pragma("unroll") for (int i_ = 0; i_ < 4; ++i_) gl16(gb_ + i_*1024, lb_ + i_*1024); \
  } while(0)

  GSTAGE(0, 0);
  asm volatile("s_waitcnt vmcnt(0)" ::: "memory");
  __syncthreads();

  int cur = 0;
  for (int kt = 0; kt < 64; ++kt){
    if (kt + 1 < 64) GSTAGE(kt + 1, cur ^ 1);
    __builtin_amdgcn_sched_barrier(0);
    bf16x8 af[2][2];
#pragma unroll
    for (int i = 0; i < 2; ++i)
#pragma unroll
      for (int ks = 0; ks < 2; ++ks){
        unsigned m = (unsigned)(wm*32 + i*16 + l16);
        unsigned off = (m*128u + (unsigned)(ks*64 + lk4*16)) ^ ((m & 7u) << 4);
        af[i][ks] = *(const bf16x8*)((const char*)&Abuf[cur][0] + off);
      }
#pragma unroll
    for (int j = 0; j < 4; ++j)
#pragma unroll
      for (int ks = 0; ks < 2; ++ks){
        unsigned n = (unsigned)(wn*64 + j*16 + l16);
        unsigned off = (n*128u + (unsigned)(ks*64 + lk4*16)) ^ ((n & 7u) << 4);
        bf16x8 bfr = *(const bf16x8*)((const char*)&Bbuf[cur][0] + off);
#pragma unroll
        for (int i = 0; i < 2; ++i)
          acc[i][j] = __builtin_amdgcn_mfma_f32_16x16x32_bf16(af[i][ks], bfr, acc[i][j], 0, 0, 0);
      }
    asm volatile("s_waitcnt vmcnt(0)" ::: "memory");
    __syncthreads();
    cur ^= 1;
  }
#undef GSTAGE

  if (EPI == 0){
    float* C = (float*)C_;
#pragma unroll
    for (int i = 0; i < 2; ++i)
#pragma unroll
      for (int j = 0; j < 4; ++j)
#pragma unroll
        for (int r = 0; r < 4; ++r){
          int row = bm*64 + wm*32 + i*16 + lk4*4 + r;
          int col = bn*128 + wn*64 + j*16 + l16;
          C[(size_t)row * HIDD + col] = acc[i][j][r];
        }
  } else {
    // RoPE epilogue: acc -> LDS [64][132] -> rotate pairs (d, d+64) -> bf16 qbf[b][h][ql][d]
    float* etile = (float*)smem;
#pragma unroll
    for (int i = 0; i < 2; ++i)
#pragma unroll
      for (int j = 0; j < 4; ++j)
#pragma unroll
        for (int r = 0; r < 4; ++r){
          int m = wm*32 + i*16 + lk4*4 + r;
          int n = wn*64 + j*16 + l16;
          etile[m*132 + n] = acc[i][j][r];
        }
    __syncthreads();
    unsigned short* Q = (unsigned short*)C_;
    int b = bm >> 1;
    int m2 = tid & 63;
    int dh = tid >> 6;
    int ql = (bm & 1)*64 + m2;
    size_t ob = ((size_t)(b*NH + bn) * QLEN + ql) * HD;
    const float scale = 0.08838834764831845f;
#pragma unroll
    for (int dd = 0; dd < 16; ++dd){
      int d = dh*16 + dd;
      float x1 = etile[m2*132 + d];
      float x2 = etile[m2*132 + d + 64];
      float c = costab[b*64 + d];
      float s = sintab[b*64 + d];
      Q[ob + d]      = f2bf((x1*c - x2*s)*scale);
      Q[ob + d + 64] = f2bf((x2*c + x1*s)*scale);
    }
  }
}

// ---------------- flash attention: KV-split, K+V double-buffered via global_load_lds ----------------
__global__ __launch_bounds__(256, 2) void attn_kernel(const unsigned short* __restrict__ Q,
                                                      const unsigned short* __restrict__ Kswz,
                                                      const unsigned short* __restrict__ V2,
                                                      const unsigned long long* __restrict__ bits,
                                                      float* __restrict__ Opart,
                                                      float* __restrict__ Mpart,
                                                      float* __restrict__ Lpart){
  __shared__ alignas(16) unsigned short Kbuf[2][8192];
  __shared__ alignas(16) unsigned short Vbuf[2][8192];
  __shared__ alignas(16) unsigned short Plds[4][1024];
  int bid = blockIdx.x;
  int j = (bid >> 3) & 7;
  int g = (bid & 7) | ((bid >> 6) << 3);
  int s   = g & 3;
  int kvh = (g >> 2) & 7;
  int b   = g >> 5;
  int hg  = j >> 1, qb = j & 1;
  int h   = kvh * 4 + hg;

  int tid = threadIdx.x, lane = tid & 63, w = tid >> 6;
  int l16 = lane & 15, lk4 = lane >> 4;

  bf16x8 qf[4];
  {
    const unsigned short* qp = Q + (((size_t)(b*NH + h) * QLEN) + qb*64 + w*16 + l16) * HD;
#pragma unroll
    for (int ks = 0; ks < 4; ++ks)
      qf[ks] = *(const bf16x8*)(qp + ks*32 + lk4*8);
  }
  f32x4 acc_o[8] = {};
  float mrun[4], lrun[4];
#pragma unroll
  for (int r = 0; r < 4; ++r){ mrun[r] = -1e30f; lrun[r] = 0.f; }

  size_t kvhbase = (size_t)(b*NKVH + kvh) * (KVLEN/64);
  const unsigned short* Ktiles = Kswz + kvhbase * 8192;
  const unsigned short* Vtiles = V2   + kvhbase * 8192;
  size_t bbase = ((size_t)(b*QLEN + qb*64 + w*16 + lk4*4)) << 6;

  const int t0 = s * (KVCHUNK/64), t1 = t0 + KVCHUNK/64;

#define STAGE(T, BUF) do { \
    const char* gk_ = (const char*)(Ktiles + (size_t)(T)*8192) + w*4096 + lane*16; \
    const char* gv_ = (const char*)(Vtiles + (size_t)(T)*8192) + w*4096 + lane*16; \
    char* lk_ = (char*)(&Kbuf[BUF][0]) + w*4096; \
    char* lv_ = (char*)(&Vbuf[BUF][0]) + w*4096; \
    _Pragma("unroll") for (int i_ = 0; i_ < 4; ++i_) gl16(gk_ + i_*1024, lk_ + i_*1024); \
    _Pragma("unroll") for (int i_ = 0; i_ < 4; ++i_) gl16(gv_ + i_*1024, lv_ + i_*1024); \
  } while(0)

  STAGE(t0, 0);
  asm volatile("s_waitcnt vmcnt(0)" ::: "memory");
  __syncthreads();

  int cur = 0;
  for (int t = t0; t < t1; ++t){
    if (t + 1 < t1) STAGE(t + 1, cur ^ 1);
    unsigned long long wrd[4];
#pragma unroll
    for (int r = 0; r < 4; ++r)
      wrd[r] = bits[bbase + (size_t)r*64 + (size_t)t];
    __builtin_amdgcn_sched_barrier(0);

    f32x4 sacc[4] = {};
#pragma unroll
    for (int nf = 0; nf < 4; ++nf){
      int krow = nf*16 + l16;
#pragma unroll
      for (int ks = 0; ks < 4; ++ks){
        unsigned byteoff = ((unsigned)krow*256u + (unsigned)(ks*32 + lk4*8)*2u) ^ (((unsigned)krow & 7u) << 4);
        bf16x8 kf = *(const bf16x8*)((const char*)&Kbuf[cur][0] + byteoff);
        sacc[nf] = __builtin_amdgcn_mfma_f32_16x16x32_bf16(qf[ks], kf, sacc[nf], 0, 0, 0);
      }
    }

    float p[4][4];
    float pmax[4];
#pragma unroll
    for (int r = 0; r < 4; ++r) pmax[r] = -1e30f;
#pragma unroll
    for (int nf = 0; nf < 4; ++nf)
#pragma unroll
      for (int r = 0; r < 4; ++r){
        bool mk = (wrd[r] >> (nf*16 + l16)) & 1ull;
        float sv = mk ? -10000.f : sacc[nf][r];
        p[nf][r] = sv;
        pmax[r] = fmaxf(pmax[r], sv);
      }
#pragma unroll
    for (int r = 0; r < 4; ++r){
#pragma unroll
      for (int mb = 1; mb < 16; mb <<= 1)
        pmax[r] = fmaxf(pmax[r], __shfl_xor(pmax[r], mb, 64));
    }
    float psum[4];
#pragma unroll
    for (int r = 0; r < 4; ++r){
      float mnew = fmaxf(mrun[r], pmax[r]);
      float corr = __expf(mrun[r] - mnew);
      mrun[r] = mnew;
      lrun[r] *= corr;
#pragma unroll
      for (int nf8 = 0; nf8 < 8; ++nf8) acc_o[nf8][r] *= corr;
      float ps = 0.f;
#pragma unroll
      for (int nf = 0; nf < 4; ++nf){
        float e = __expf(p[nf][r] - mnew);
        p[nf][r] = e;
        ps += e;
      }
      psum[r] = ps;
    }
#pragma unroll
    for (int r = 0; r < 4; ++r){
#pragma unroll
      for (int mb = 1; mb < 16; mb <<= 1)
        psum[r] += __shfl_xor(psum[r], mb, 64);
      lrun[r] += psum[r];
    }

    unsigned short* pw = &Plds[w][0];
#pragma unroll
    for (int nf = 0; nf < 4; ++nf)
#pragma unroll
      for (int r = 0; r < 4; ++r){
        unsigned prow = (unsigned)(lk4*4 + r);
        unsigned pcol = (unsigned)(nf*16 + l16);
        unsigned byteoff = (prow*128u + pcol*2u) ^ ((prow & 7u) << 4);
        *(unsigned short*)((char*)pw + byteoff) = f2bf(p[nf][r]);
      }
    __builtin_amdgcn_sched_barrier(0);
    asm volatile("s_waitcnt lgkmcnt(0)" ::: "memory");
    __builtin_amdgcn_sched_barrier(0);

    bf16x8 pf[2];
#pragma unroll
    for (int ks2 = 0; ks2 < 2; ++ks2){
      unsigned byteoff = ((unsigned)l16*128u + (unsigned)(ks2*32 + lk4*8)*2u) ^ (((unsigned)l16 & 7u) << 4);
      pf[ks2] = *(const bf16x8*)((const char*)pw + byteoff);
    }
#pragma unroll
    for (int nf8 = 0; nf8 < 8; ++nf8)
#pragma unroll
      for (int ks2 = 0; ks2 < 2; ++ks2){
        unsigned byteoff = (unsigned)(nf8*2 + ks2)*1024u + (unsigned)lane*16u;
        bf16x8 vf = *(const bf16x8*)((const char*)&Vbuf[cur][0] + byteoff);
        acc_o[nf8] = __builtin_amdgcn_mfma_f32_16x16x32_bf16(pf[ks2], vf, acc_o[nf8], 0, 0, 0);
      }

    asm volatile("s_waitcnt vmcnt(0)" ::: "memory");
    __syncthreads();
    cur ^= 1;
  }
#undef STAGE

  size_t rowbase = ((size_t)(s*4 + b) * NH + h) * QLEN + qb*64 + w*16 + lk4*4;
#pragma unroll
  for (int nf8 = 0; nf8 < 8; ++nf8)
#pragma unroll
    for (int r = 0; r < 4; ++r){
      int col = nf8*16 + l16;
      Opart[(rowbase + r) * HD + col] = acc_o[nf8][r];
    }
  if (l16 == 0){
#pragma unroll
    for (int r = 0; r < 4; ++r){
      Mpart[rowbase + r] = mrun[r];
      Lpart[rowbase + r] = lrun[r];
    }
  }
}

// ---------------- combine: merge NSPLIT partials -> bf16 A-image for GEMM2 ----------------
__global__ __launch_bounds__(256) void combine_kernel(const float* __restrict__ Opart,
                                                      const float* __restrict__ Mpart,
                                                      const float* __restrict__ Lpart,
                                                      unsigned short* __restrict__ A2img){
  int idx = blockIdx.x * 256 + threadIdx.x;
  int d4 = idx & 31;
  int row = idx >> 5;                       // (b*32+h)*128 + ql
  const int RS = 4 * NH * QLEN;
  float m[NSPLIT];
#pragma unroll
  for (int s = 0; s < NSPLIT; ++s) m[s] = Mpart[(size_t)s*RS + row];
  float M = fmaxf(fmaxf(m[0], m[1]), fmaxf(m[2], m[3]));
  float L = 0.f;
  f32x4 num = {};
#pragma unroll
  for (int s = 0; s < NSPLIT; ++s){
    float wsc = __expf(m[s] - M);
    L += wsc * Lpart[(size_t)s*RS + row];
    f32x4 o = *(const f32x4*)&Opart[((size_t)s*RS + row) * HD + d4*4];
#pragma unroll
    for (int t = 0; t < 4; ++t) num[t] += wsc * o[t];
  }
  int ql = row & 127, h = (row >> 7) & 31, b = row >> 12;
  // A-image coords: global row g = b*128+ql, col k = h*128 + d4*4
  int bm = b*2 + (ql >> 6), mm = ql & 63;
  int kt = h*2 + (d4 >> 4), kl = (d4*4) & 63;
  s16x4 res;
#pragma unroll
  for (int t = 0; t < 4; ++t) res[t] = (short)f2bf(num[t] / L);
  char* tile = (char*)A2img + (size_t)(bm*64 + kt) * 8192;
  unsigned off = ((unsigned)(mm*128 + kl*2)) ^ (((unsigned)mm & 7u) << 4);
  *(s16x4*)(tile + off) = res;
}

// ---------------- launch ----------------
extern "C" void kernel_launch(void* const* d_in, const int* in_sizes, int n_in,
                              void* d_out, int out_size, void* d_ws, size_t ws_size,
                              hipStream_t stream){
  (void)in_sizes; (void)n_in; (void)out_size; (void)ws_size;
  const float* hidden = (const float*)d_in[0];
  const float* kst    = (const float*)d_in[1];
  const float* vst    = (const float*)d_in[2];
  const float* wq     = (const float*)d_in[3];
  const float* wo     = (const float*)d_in[4];
  const void*  pos    = d_in[5];
  const void*  mask   = d_in[6];
  float* out = (float*)d_out;

  char* ws = (char*)d_ws;
  unsigned short* Kswz  = (unsigned short*)ws;                   // 32 MiB
  unsigned short* V2    = (unsigned short*)(ws + (32u << 20));   // 32 MiB
  unsigned short* WoImg = (unsigned short*)(ws + (64u << 20));   // 32 MiB
  unsigned short* WqImg = (unsigned short*)(ws + (96u << 20));   // 32 MiB (dead after GEMM1)
  float*          Opart = (float*)(ws + (96u << 20));            // 32 MiB overlay on WqImg
  unsigned short* A1img = (unsigned short*)(ws + (128u << 20));  // 4 MiB
  unsigned short* qbf   = (unsigned short*)(ws + (132u << 20));  // 4 MiB
  unsigned short* A2img = (unsigned short*)(ws + (136u << 20));  // 4 MiB
  float* Mpart = (float*)(ws + (140u << 20));                    // 256 KiB
  float* Lpart = (float*)(ws + (140u << 20) + (256u << 10));     // 256 KiB
  unsigned long long* bits = (unsigned long long*)(ws + (140u << 20) + (512u << 10)); // 256 KiB
  float* costab = (float*)(ws + (140u << 20) + (768u << 10));
  float* sintab = costab + 256;
  int*   flags  = (int*)(sintab + 256);

  prep_kernel<<<1, 256, 0, stream>>>((const int*)pos, (const unsigned int*)mask,
                                     costab, sintab, flags);
  maskpack_kernel<<<8192, 256, 0, stream>>>(mask, flags, bits);
  kvprep_kernel<<<2048, 256, 0, stream>>>(kst, vst, Kswz, V2);
  wprep_kernel<<<4608, 256, 0, stream>>>(wq, wo, hidden, WqImg, WoImg, A1img);
  gemm_kernel<1><<<256, 256, 0, stream>>>(A1img, WqImg, qbf, costab, sintab);
  attn_kernel<<<1024, 256, 0, stream>>>(qbf, Kswz, V2, bits, Opart, Mpart, Lpart);
  combine_kernel<<<2048, 256, 0, stream>>>(Opart, Mpart, Lpart, A2img);
  gemm_kernel<0><<<256, 256, 0, stream>>>(A2img, WoImg, out, nullptr, nullptr);
}

// Round 6
// 235.678 us; speedup vs baseline: 2.5282x; 1.1352x over previous
//
#include <hip/hip_runtime.h>
#include <math.h>

typedef __attribute__((ext_vector_type(8))) short bf16x8;
typedef __attribute__((ext_vector_type(4))) float f32x4;
typedef __attribute__((ext_vector_type(4))) short s16x4;
typedef __attribute__((ext_vector_type(4))) int i32x4;

__device__ inline unsigned short f2bf(float x){
  unsigned u = __builtin_bit_cast(unsigned, x);
  u = (u + 0x7FFFu + ((u >> 16) & 1u)) >> 16;
  return (unsigned short)u;
}
__device__ inline unsigned pk2bf(float lo, float hi){
  return (unsigned)f2bf(lo) | ((unsigned)f2bf(hi) << 16);
}

__device__ inline void gl16(const void* g, void* l){
  __builtin_amdgcn_global_load_lds(
      (const __attribute__((address_space(1))) unsigned int*)g,
      (__attribute__((address_space(3))) unsigned int*)l, 16, 0, 0);
}

#define KVLEN 4096
#define QLEN  128
#define NH    32
#define NKVH  8
#define HD    128
#define HIDD  4096
#define NSPLIT 4
#define KVCHUNK (KVLEN / NSPLIT)

// ---------------- prep: dtype detection + per-batch RoPE tables ----------------
__global__ void prep_kernel(const int* __restrict__ pos32,
                            const unsigned int* __restrict__ mask32,
                            float* __restrict__ costab,
                            float* __restrict__ sintab,
                            int* __restrict__ flags){
  int tid = threadIdx.x;
  if (tid < 64){
    unsigned long long bal = __ballot((mask32[tid] & 0xFFFFFF00u) != 0);
    if (tid == 0) flags[0] = (bal != 0) ? 1 : 0;
  }
  int b = tid >> 6, j = tid & 63;
  bool pos64 = (pos32[2*4095 + 1] == 0);
  long long mpos;
  if (pos64) mpos = ((const long long*)pos32)[(size_t)b*KVLEN + KVLEN - 1];
  else       mpos = (long long)pos32[(size_t)b*KVLEN + KVLEN - 1];
  double inv = pow(10000.0, -((double)j) / 64.0);
  double ang = (double)mpos * inv;
  costab[b*64 + j] = (float)cos(ang);
  sintab[b*64 + j] = (float)sin(ang);
}

// ---------------- mask pack: bool[B,1,QL,KVL] -> u64 bitmask ----------------
__global__ __launch_bounds__(256) void maskpack_kernel(const void* __restrict__ mask,
                                                       const int* __restrict__ flags,
                                                       unsigned long long* __restrict__ bits){
  int idx = blockIdx.x * 256 + threadIdx.x;
  bool m8 = (flags[0] != 0);
  bool v = m8 ? (((const unsigned char*)mask)[idx] != 0)
              : (((const int*)mask)[idx] != 0);
  unsigned long long bal = __ballot(v);
  if ((threadIdx.x & 63) == 0) bits[idx >> 6] = bal;
}

// ---------------- kvprep: fp32 K,V -> bf16 attn-ready tile images ----------------
__global__ __launch_bounds__(256) void kvprep_kernel(const float* __restrict__ Kg,
                                                     const float* __restrict__ Vg,
                                                     unsigned short* __restrict__ Kswz,
                                                     unsigned short* __restrict__ V2){
  __shared__ alignas(16) char tl[16384];
  int bid = blockIdx.x;
  int tid = threadIdx.x;
  const float* kin = Kg + (size_t)bid * 8192;
  const float* vin = Vg + (size_t)bid * 8192;
  unsigned short* kout = Kswz + (size_t)bid * 8192;
  unsigned short* vout = V2   + (size_t)bid * 8192;
#pragma unroll
  for (int i = 0; i < 4; ++i){
    int c = tid + 256*i;
    int r = c >> 4, d0 = (c & 15) * 8;
    f32x4 x0 = *(const f32x4*)(kin + r*128 + d0);
    f32x4 x1 = *(const f32x4*)(kin + r*128 + d0 + 4);
    bf16x8 s;
#pragma unroll
    for (int t = 0; t < 4; ++t){ s[t] = (short)f2bf(x0[t]); s[t+4] = (short)f2bf(x1[t]); }
    unsigned o = ((unsigned)(r*256 + d0*2)) ^ (((unsigned)r & 7u) << 4);
    *(bf16x8*)(tl + o) = s;
  }
  __syncthreads();
#pragma unroll
  for (int i = 0; i < 4; ++i)
    *(bf16x8*)((char*)kout + tid*16 + i*4096) = *(const bf16x8*)(tl + tid*16 + i*4096);
#pragma unroll
  for (int i = 0; i < 4; ++i){
    int c = tid + 256*i;
    int l16 = c & 15, lk4 = (c >> 4) & 3, ks2 = (c >> 6) & 1, nf8 = c >> 7;
    int d = nf8*16 + l16;
    int kvb = ks2*32 + lk4*8;
    bf16x8 s;
#pragma unroll
    for (int e = 0; e < 8; ++e) s[e] = (short)f2bf(vin[(size_t)(kvb + e)*128 + d]);
    *(bf16x8*)(vout + (size_t)c*8) = s;
  }
}

// ---------------- wprep: weights/hidden fp32 -> bf16 swizzled tile images ----------------
__global__ __launch_bounds__(256) void wprep_kernel(const float* __restrict__ Wq,
                                                    const float* __restrict__ Wo,
                                                    const float* __restrict__ hidden,
                                                    unsigned short* __restrict__ WqImg,
                                                    unsigned short* __restrict__ WoImg,
                                                    unsigned short* __restrict__ A1img){
  __shared__ alignas(16) char tl[16384];
  int bid = blockIdx.x, tid = threadIdx.x;
  if (bid < 4096){
    const float* W = (bid < 2048) ? Wq : Wo;
    unsigned short* img = (bid < 2048) ? WqImg : WoImg;
    int t = bid & 2047;
    int bn = t >> 6, kt = t & 63;
    char* outB = (char*)img + (size_t)t * 16384;
#pragma unroll
    for (int i = 0; i < 4; ++i){
      int c = tid + 256*i;
      int n = c & 127, kc = c >> 7;
      const float* src = W + (size_t)(kt*64 + kc*8) * HIDD + bn*128 + n;
      bf16x8 s;
#pragma unroll
      for (int e = 0; e < 8; ++e) s[e] = (short)f2bf(src[(size_t)e * HIDD]);
      unsigned off = ((unsigned)(n*128 + kc*16)) ^ (((unsigned)n & 7u) << 4);
      *(bf16x8*)(tl + off) = s;
    }
    __syncthreads();
#pragma unroll
    for (int i = 0; i < 4; ++i)
      *(bf16x8*)(outB + tid*16 + i*4096) = *(const bf16x8*)(tl + tid*16 + i*4096);
  } else {
    int t = bid - 4096;
    int bm = t >> 6, kt = t & 63;
    char* outA = (char*)A1img + (size_t)t * 8192;
#pragma unroll
    for (int i = 0; i < 2; ++i){
      int c = tid + 256*i;
      int m = c >> 3, kc = c & 7;
      const float* src = hidden + (size_t)(bm*64 + m) * HIDD + kt*64 + kc*8;
      f32x4 x0 = *(const f32x4*)src;
      f32x4 x1 = *(const f32x4*)(src + 4);
      bf16x8 s;
#pragma unroll
      for (int e = 0; e < 4; ++e){ s[e] = (short)f2bf(x0[e]); s[e+4] = (short)f2bf(x1[e]); }
      unsigned off = ((unsigned)(m*128 + kc*16)) ^ (((unsigned)m & 7u) << 4);
      *(bf16x8*)(tl + off) = s;
    }
    __syncthreads();
#pragma unroll
    for (int i = 0; i < 2; ++i)
      *(bf16x8*)(outA + tid*16 + i*4096) = *(const bf16x8*)(tl + tid*16 + i*4096);
  }
}

// ---------------- GEMM: 512x4096x4096, bf16 images, quad-buffered counted-vmcnt ----------------
// BM=64 BN=128 BK=64, 4 waves 2x2. EPI=0: fp32 C. EPI=1: RoPE via LDS roundtrip -> qbf.
template<int EPI>
__global__ __launch_bounds__(256) void gemm_kernel(const unsigned short* __restrict__ Aimg,
                                                   const unsigned short* __restrict__ Bimg,
                                                   void* __restrict__ C_,
                                                   const float* __restrict__ costab,
                                                   const float* __restrict__ sintab){
  __shared__ alignas(16) char smem[98304];            // 4 x (A 8KB + B 16KB)
  int bid = blockIdx.x;
  int bn = (bid & 7) | ((bid >> 6) << 3);
  int bm = (bid >> 3) & 7;
  int tid = threadIdx.x, lane = tid & 63, w = tid >> 6;
  int wm = w >> 1, wn = w & 1;
  int l16 = lane & 15, lk4 = lane >> 4;
  const char* At = (const char*)Aimg + (size_t)bm * 64 * 8192;
  const char* Bt = (const char*)Bimg + (size_t)bn * 64 * 16384;
  f32x4 acc[2][4] = {};

#define GSTAGE(KT, BUF) do { \
    const char* ga_ = At + (size_t)(KT)*8192  + w*2048 + lane*16; \
    const char* gb_ = Bt + (size_t)(KT)*16384 + w*4096 + lane*16; \
    char* la_ = smem + (BUF)*24576 + w*2048; \
    char* lb_ = smem + (BUF)*24576 + 8192 + w*4096; \
    gl16(ga_, la_); gl16(ga_ + 1024, la_ + 1024); \
    _Pragma("unroll") for (int i_ = 0; i_ < 4; ++i_) gl16(gb_ + i_*1024, lb_ + i_*1024); \
  } while(0)

  GSTAGE(0, 0); GSTAGE(1, 1); GSTAGE(2, 2);

  for (int kt = 0; kt < 64; ++kt){
    if (kt + 2 < 64)      asm volatile("s_waitcnt vmcnt(12)" ::: "memory");
    else if (kt + 1 < 64) asm volatile("s_waitcnt vmcnt(6)" ::: "memory");
    else                  asm volatile("s_waitcnt vmcnt(0)" ::: "memory");
    __syncthreads();
    if (kt + 3 < 64) GSTAGE(kt + 3, (kt + 3) & 3);
    const char* Ab = smem + (kt & 3)*24576;
    const char* Bb = Ab + 8192;
    bf16x8 af[2][2];
#pragma unroll
    for (int i = 0; i < 2; ++i)
#pragma unroll
      for (int ks = 0; ks < 2; ++ks){
        unsigned m = (unsigned)(wm*32 + i*16 + l16);
        unsigned off = (m*128u + (unsigned)(ks*64 + lk4*16)) ^ ((m & 7u) << 4);
        af[i][ks] = *(const bf16x8*)(Ab + off);
      }
#pragma unroll
    for (int j = 0; j < 4; ++j)
#pragma unroll
      for (int ks = 0; ks < 2; ++ks){
        unsigned n = (unsigned)(wn*64 + j*16 + l16);
        unsigned off = (n*128u + (unsigned)(ks*64 + lk4*16)) ^ ((n & 7u) << 4);
        bf16x8 bfr = *(const bf16x8*)(Bb + off);
#pragma unroll
        for (int i = 0; i < 2; ++i)
          acc[i][j] = __builtin_amdgcn_mfma_f32_16x16x32_bf16(af[i][ks], bfr, acc[i][j], 0, 0, 0);
      }
  }
#undef GSTAGE

  if (EPI == 0){
    float* C = (float*)C_;
#pragma unroll
    for (int i = 0; i < 2; ++i)
#pragma unroll
      for (int j = 0; j < 4; ++j)
#pragma unroll
        for (int r = 0; r < 4; ++r){
          int row = bm*64 + wm*32 + i*16 + lk4*4 + r;
          int col = bn*128 + wn*64 + j*16 + l16;
          C[(size_t)row * HIDD + col] = acc[i][j][r];
        }
  } else {
    float* etile = (float*)smem;
    __syncthreads();
#pragma unroll
    for (int i = 0; i < 2; ++i)
#pragma unroll
      for (int j = 0; j < 4; ++j)
#pragma unroll
        for (int r = 0; r < 4; ++r){
          int m = wm*32 + i*16 + lk4*4 + r;
          int n = wn*64 + j*16 + l16;
          etile[m*132 + n] = acc[i][j][r];
        }
    __syncthreads();
    unsigned short* Q = (unsigned short*)C_;
    int b = bm >> 1;
    int m2 = tid & 63;
    int dh = tid >> 6;
    int ql = (bm & 1)*64 + m2;
    size_t ob = ((size_t)(b*NH + bn) * QLEN + ql) * HD;
    const float scale = 0.08838834764831845f;
#pragma unroll
    for (int dd = 0; dd < 16; ++dd){
      int d = dh*16 + dd;
      float x1 = etile[m2*132 + d];
      float x2 = etile[m2*132 + d + 64];
      float c = costab[b*64 + d];
      float s = sintab[b*64 + d];
      Q[ob + d]      = f2bf((x1*c - x2*s)*scale);
      Q[ob + d + 64] = f2bf((x2*c + x1*s)*scale);
    }
  }
}

// ---------------- flash attention: swapped QK^T, in-register P, full head per block ----
// grid 512 = (s,b,kvh) groups x 4 heads; 4 waves x 32 q-rows. O^T accumulators.
__global__ __launch_bounds__(256, 2) void attn_kernel(const unsigned short* __restrict__ Q,
                                                      const unsigned short* __restrict__ Kswz,
                                                      const unsigned short* __restrict__ V2,
                                                      const unsigned long long* __restrict__ bits,
                                                      float* __restrict__ Opart,
                                                      float* __restrict__ Mpart,
                                                      float* __restrict__ Lpart){
  __shared__ alignas(16) unsigned short Kbuf[2][8192];
  __shared__ alignas(16) unsigned short Vbuf[2][8192];
  int bid = blockIdx.x;
  int g = (bid & 7) | ((bid >> 5) << 3);     // (s,b,kvh): 4 head-sharers -> same XCD
  int j = (bid >> 3) & 3;
  int s   = g & 3;
  int kvh = (g >> 2) & 7;
  int b   = g >> 5;
  int h   = kvh * 4 + j;

  int tid = threadIdx.x, lane = tid & 63, w = tid >> 6;
  int l16 = lane & 15, lk4 = lane >> 4;
  int lk4x4 = lk4 * 4;

  // Q fragments (B-operand) for both 16-row groups
  bf16x8 qf[2][4];
#pragma unroll
  for (int qg = 0; qg < 2; ++qg){
    const unsigned short* qp = Q + (((size_t)(b*NH + h) * QLEN) + w*32 + qg*16 + l16) * HD;
#pragma unroll
    for (int ks = 0; ks < 4; ++ks)
      qf[qg][ks] = *(const bf16x8*)(qp + ks*32 + lk4*8);
  }
  f32x4 acc_o[2][8] = {};
  float mrun[2] = {-1e30f, -1e30f}, lrun[2] = {0.f, 0.f};

  size_t kvhbase = (size_t)(b*NKVH + kvh) * (KVLEN/64);
  const unsigned short* Ktiles = Kswz + kvhbase * 8192;
  const unsigned short* Vtiles = V2   + kvhbase * 8192;
  size_t qrow0 = (size_t)(b*QLEN + w*32 + l16);     // mask row, qg=0

  const int t0 = s * (KVCHUNK/64), t1 = t0 + KVCHUNK/64;
  int srcb0 = (l16 + ((lk4 & 1) << 5)) << 2;        // bpermute byte addr
  int srcb1 = srcb0 + 64;

#define STAGE(T, BUF) do { \
    const char* gk_ = (const char*)(Ktiles + (size_t)(T)*8192) + w*4096 + lane*16; \
    const char* gv_ = (const char*)(Vtiles + (size_t)(T)*8192) + w*4096 + lane*16; \
    char* lk_ = (char*)(&Kbuf[BUF][0]) + w*4096; \
    char* lv_ = (char*)(&Vbuf[BUF][0]) + w*4096; \
    _Pragma("unroll") for (int i_ = 0; i_ < 4; ++i_) gl16(gk_ + i_*1024, lk_ + i_*1024); \
    _Pragma("unroll") for (int i_ = 0; i_ < 4; ++i_) gl16(gv_ + i_*1024, lv_ + i_*1024); \
  } while(0)

  STAGE(t0, 0);
  int cur = 0;
  for (int t = t0; t < t1; ++t){
    asm volatile("s_waitcnt vmcnt(0)" ::: "memory");   // aged a full tile
    __syncthreads();
    if (t + 1 < t1) STAGE(t + 1, cur ^ 1);

    unsigned long long wrd[2];
    wrd[0] = bits[qrow0*64 + (size_t)t];
    wrd[1] = bits[(qrow0 + 16)*64 + (size_t)t];

    // ---- S^T = K Q (swapped): sacc[qg][nf][r] = S[kv=nf*16+lk4*4+r][q=l16] ----
    f32x4 sacc[2][4] = {};
#pragma unroll
    for (int nf = 0; nf < 4; ++nf){
      int krow = nf*16 + l16;
#pragma unroll
      for (int ks = 0; ks < 4; ++ks){
        unsigned byteoff = ((unsigned)krow*256u + (unsigned)(ks*32 + lk4*8)*2u) ^ (((unsigned)krow & 7u) << 4);
        bf16x8 kf = *(const bf16x8*)((const char*)&Kbuf[cur][0] + byteoff);
        sacc[0][nf] = __builtin_amdgcn_mfma_f32_16x16x32_bf16(kf, qf[0][ks], sacc[0][nf], 0, 0, 0);
        sacc[1][nf] = __builtin_amdgcn_mfma_f32_16x16x32_bf16(kf, qf[1][ks], sacc[1][nf], 0, 0, 0);
      }
    }

    // ---- softmax (lane-local rows) + pack to bf16 pairs ----
    unsigned P32[2][8];
#pragma unroll
    for (int qg = 0; qg < 2; ++qg){
      float p[4][4];
      float pm = -1e30f;
#pragma unroll
      for (int nf = 0; nf < 4; ++nf)
#pragma unroll
        for (int r = 0; r < 4; ++r){
          bool mk = (wrd[qg] >> (nf*16 + lk4x4 + r)) & 1ull;
          float sv = mk ? -10000.f : sacc[qg][nf][r];
          p[nf][r] = sv;
          pm = fmaxf(pm, sv);
        }
      pm = fmaxf(pm, __shfl_xor(pm, 16, 64));
      pm = fmaxf(pm, __shfl_xor(pm, 32, 64));
      float mnew = fmaxf(mrun[qg], pm);
      float corr = __expf(mrun[qg] - mnew);
      mrun[qg] = mnew;
      float ps = 0.f;
#pragma unroll
      for (int nf = 0; nf < 4; ++nf)
#pragma unroll
        for (int r = 0; r < 4; ++r){
          float e = __expf(p[nf][r] - mnew);
          p[nf][r] = e;
          ps += e;
        }
      ps += __shfl_xor(ps, 16, 64);
      ps += __shfl_xor(ps, 32, 64);
      lrun[qg] = lrun[qg]*corr + ps;
#pragma unroll
      for (int nf8 = 0; nf8 < 8; ++nf8)
#pragma unroll
        for (int r = 0; r < 4; ++r) acc_o[qg][nf8][r] *= corr;
#pragma unroll
      for (int nf = 0; nf < 4; ++nf){
        P32[qg][nf*2]     = pk2bf(p[nf][0], p[nf][1]);
        P32[qg][nf*2 + 1] = pk2bf(p[nf][2], p[nf][3]);
      }
    }

    // ---- cross-lane exchange: build PV B-fragments via ds_bpermute ----
    bf16x8 pf[2][2];
    bool hi = lk4 >= 2;
#pragma unroll
    for (int qg = 0; qg < 2; ++qg)
#pragma unroll
      for (int ks2 = 0; ks2 < 2; ++ks2){
        int a0 = __builtin_amdgcn_ds_bpermute(srcb0, (int)P32[qg][ks2*4 + 0]);
        int b0 = __builtin_amdgcn_ds_bpermute(srcb0, (int)P32[qg][ks2*4 + 2]);
        int a1 = __builtin_amdgcn_ds_bpermute(srcb0, (int)P32[qg][ks2*4 + 1]);
        int b1 = __builtin_amdgcn_ds_bpermute(srcb0, (int)P32[qg][ks2*4 + 3]);
        int a2 = __builtin_amdgcn_ds_bpermute(srcb1, (int)P32[qg][ks2*4 + 0]);
        int b2 = __builtin_amdgcn_ds_bpermute(srcb1, (int)P32[qg][ks2*4 + 2]);
        int a3 = __builtin_amdgcn_ds_bpermute(srcb1, (int)P32[qg][ks2*4 + 1]);
        int b3 = __builtin_amdgcn_ds_bpermute(srcb1, (int)P32[qg][ks2*4 + 3]);
        i32x4 wv = { hi ? b0 : a0, hi ? b1 : a1, hi ? b2 : a2, hi ? b3 : a3 };
        pf[qg][ks2] = __builtin_bit_cast(bf16x8, wv);
      }

    // ---- O^T += V^T P^T ----
#pragma unroll
    for (int nf8 = 0; nf8 < 8; ++nf8)
#pragma unroll
      for (int ks2 = 0; ks2 < 2; ++ks2){
        unsigned byteoff = (unsigned)(nf8*2 + ks2)*1024u + (unsigned)lane*16u;
        bf16x8 vf = *(const bf16x8*)((const char*)&Vbuf[cur][0] + byteoff);
        acc_o[0][nf8] = __builtin_amdgcn_mfma_f32_16x16x32_bf16(vf, pf[0][ks2], acc_o[0][nf8], 0, 0, 0);
        acc_o[1][nf8] = __builtin_amdgcn_mfma_f32_16x16x32_bf16(vf, pf[1][ks2], acc_o[1][nf8], 0, 0, 0);
      }
    cur ^= 1;
  }
#undef STAGE

  // ---- epilogue: O^T lane layout -> Opart rows; (m,l) scalar per lane ----
  size_t rowbase = ((size_t)(s*4 + b) * NH + h) * QLEN + w*32 + l16;
#pragma unroll
  for (int qg = 0; qg < 2; ++qg){
    size_t row = rowbase + qg*16;
#pragma unroll
    for (int nf8 = 0; nf8 < 8; ++nf8)
      *(f32x4*)&Opart[row * HD + nf8*16 + lk4x4] = acc_o[qg][nf8];
    if (lk4 == 0){
      Mpart[row] = mrun[qg];
      Lpart[row] = lrun[qg];
    }
  }
}

// ---------------- combine: merge NSPLIT partials -> bf16 A-image for GEMM2 ----------------
__global__ __launch_bounds__(256) void combine_kernel(const float* __restrict__ Opart,
                                                      const float* __restrict__ Mpart,
                                                      const float* __restrict__ Lpart,
                                                      unsigned short* __restrict__ A2img){
  int idx = blockIdx.x * 256 + threadIdx.x;
  int d4 = idx & 31;
  int row = idx >> 5;
  const int RS = 4 * NH * QLEN;
  float m[NSPLIT];
#pragma unroll
  for (int s = 0; s < NSPLIT; ++s) m[s] = Mpart[(size_t)s*RS + row];
  float M = fmaxf(fmaxf(m[0], m[1]), fmaxf(m[2], m[3]));
  float L = 0.f;
  f32x4 num = {};
#pragma unroll
  for (int s = 0; s < NSPLIT; ++s){
    float wsc = __expf(m[s] - M);
    L += wsc * Lpart[(size_t)s*RS + row];
    f32x4 o = *(const f32x4*)&Opart[((size_t)s*RS + row) * HD + d4*4];
#pragma unroll
    for (int t = 0; t < 4; ++t) num[t] += wsc * o[t];
  }
  int ql = row & 127, h = (row >> 7) & 31, b = row >> 12;
  int bm = b*2 + (ql >> 6), mm = ql & 63;
  int kt = h*2 + (d4 >> 4), kl = (d4*4) & 63;
  s16x4 res;
#pragma unroll
  for (int t = 0; t < 4; ++t) res[t] = (short)f2bf(num[t] / L);
  char* tile = (char*)A2img + (size_t)(bm*64 + kt) * 8192;
  unsigned off = ((unsigned)(mm*128 + kl*2)) ^ (((unsigned)mm & 7u) << 4);
  *(s16x4*)(tile + off) = res;
}

// ---------------- launch ----------------
extern "C" void kernel_launch(void* const* d_in, const int* in_sizes, int n_in,
                              void* d_out, int out_size, void* d_ws, size_t ws_size,
                              hipStream_t stream){
  (void)in_sizes; (void)n_in; (void)out_size; (void)ws_size;
  const float* hidden = (const float*)d_in[0];
  const float* kst    = (const float*)d_in[1];
  const float* vst    = (const float*)d_in[2];
  const float* wq     = (const float*)d_in[3];
  const float* wo     = (const float*)d_in[4];
  const void*  pos    = d_in[5];
  const void*  mask   = d_in[6];
  float* out = (float*)d_out;

  char* ws = (char*)d_ws;
  unsigned short* Kswz  = (unsigned short*)ws;                   // 32 MiB
  unsigned short* V2    = (unsigned short*)(ws + (32u << 20));   // 32 MiB
  unsigned short* WoImg = (unsigned short*)(ws + (64u << 20));   // 32 MiB
  unsigned short* WqImg = (unsigned short*)(ws + (96u << 20));   // 32 MiB (dead after GEMM1)
  float*          Opart = (float*)(ws + (96u << 20));            // 32 MiB overlay on WqImg
  unsigned short* A1img = (unsigned short*)(ws + (128u << 20));  // 4 MiB
  unsigned short* qbf   = (unsigned short*)(ws + (132u << 20));  // 4 MiB
  unsigned short* A2img = (unsigned short*)(ws + (136u << 20));  // 4 MiB
  float* Mpart = (float*)(ws + (140u << 20));                    // 256 KiB
  float* Lpart = (float*)(ws + (140u << 20) + (256u << 10));     // 256 KiB
  unsigned long long* bits = (unsigned long long*)(ws + (140u << 20) + (512u << 10)); // 256 KiB
  float* costab = (float*)(ws + (140u << 20) + (768u << 10));
  float* sintab = costab + 256;
  int*   flags  = (int*)(sintab + 256);

  prep_kernel<<<1, 256, 0, stream>>>((const int*)pos, (const unsigned int*)mask,
                                     costab, sintab, flags);
  maskpack_kernel<<<8192, 256, 0, stream>>>(mask, flags, bits);
  kvprep_kernel<<<2048, 256, 0, stream>>>(kst, vst, Kswz, V2);
  wprep_kernel<<<4608, 256, 0, stream>>>(wq, wo, hidden, WqImg, WoImg, A1img);
  gemm_kernel<1><<<256, 256, 0, stream>>>(A1img, WqImg, qbf, costab, sintab);
  attn_kernel<<<512, 256, 0, stream>>>(qbf, Kswz, V2, bits, Opart, Mpart, Lpart);
  combine_kernel<<<2048, 256, 0, stream>>>(Opart, Mpart, Lpart, A2img);
  gemm_kernel<0><<<256, 256, 0, stream>>>(A2img, WoImg, out, nullptr, nullptr);
}